// Round 9
// baseline (219.495 us; speedup 1.0000x reference)
//
#include <hip/hip_runtime.h>

typedef float f32x4 __attribute__((ext_vector_type(4)));

// 16-segment breakpoints (module constants from the reference)
__device__ __constant__ float c_seg[16] = {
    0.0001f, 0.002f, 0.004f, 0.007f, 0.01f, 0.03f, 0.1f, 0.2f,
    0.3f,    1.0f,   2.0f,   4.0f,   8.0f,  16.0f, 64.0f, 1024.0f};

__device__ __forceinline__ float eval_seg(float x,
                                          const float* __restrict__ s_seg,
                                          const float* __restrict__ s_y0,
                                          const float* __restrict__ s_k) {
    float xc = fminf(fmaxf(x, 0.0001f), 1024.0f);
    // searchsorted(side='left') - 1, clamped to [0,14]
    int idx = 0;
    idx += (xc > 0.002f);
    idx += (xc > 0.004f);
    idx += (xc > 0.007f);
    idx += (xc > 0.01f);
    idx += (xc > 0.03f);
    idx += (xc > 0.1f);
    idx += (xc > 0.2f);
    idx += (xc > 0.3f);
    idx += (xc > 1.0f);
    idx += (xc > 2.0f);
    idx += (xc > 4.0f);
    idx += (xc > 8.0f);
    idx += (xc > 16.0f);
    idx += (xc > 64.0f);
    // 16 words in 16 distinct banks -> conflict-free gather (R7: replacing
    // DS with a cndmask-cascade was net-worse, 212 vs 200 us)
    float x0 = s_seg[idx];
    float y0 = s_y0[idx];
    float k  = s_k[idx];
    return fmaf(xc - x0, k, y0);
}

__device__ __forceinline__ f32x4 eval4(f32x4 v,
                                       const float* __restrict__ s_seg,
                                       const float* __restrict__ s_y0,
                                       const float* __restrict__ s_k) {
    f32x4 r;
    r.x = eval_seg(v.x, s_seg, s_y0, s_k);
    r.y = eval_seg(v.y, s_seg, s_y0, s_k);
    r.z = eval_seg(v.z, s_seg, s_y0, s_k);
    r.w = eval_seg(v.w, s_seg, s_y0, s_k);
    return r;
}

// R8 (+3%): wave-contiguous x4 unroll, 4 KB window/iter. R9 change: make the
// wave's ITERATIONS sequential too — block owns a contiguous 256 KB chunk,
// each wave walks its own 64 KB sub-span ascending (16 iters x 4 KB). Every
// wave is now a pure ascending-address stream (same shape as the 6.7 TB/s
// fill). (256,8) pins <=64 VGPRs (R2's occupancy-cliff guard).
#define WAVE_SPAN 4096   // f32x4 per wave chunk (64 KB)
#define BLK_SPAN  16384  // f32x4 per block chunk (256 KB) = 4 waves

__global__ __launch_bounds__(256, 8) void invsqrt16_kernel(
        const f32x4* __restrict__ x, f32x4* __restrict__ out, int n4) {
    __shared__ float s_seg[16];
    __shared__ float s_y0[16];
    __shared__ float s_k[16];
    if (threadIdx.x < 16) {
        int j = threadIdx.x;
        float s0 = c_seg[j];
        float s1 = c_seg[(j < 15) ? j + 1 : 15];
        float y0 = 1.0f / sqrtf(s0);
        float y1 = 1.0f / sqrtf(s1);
        s_seg[j] = s0;
        s_y0[j]  = y0;
        s_k[j]   = (j < 15) ? (y1 - y0) / (s1 - s0) : 0.0f;
    }
    __syncthreads();

    const int lane = threadIdx.x & 63;
    const int wave = threadIdx.x >> 6;
    const int gstride = gridDim.x * BLK_SPAN;

    for (int chunk = blockIdx.x * BLK_SPAN; chunk < n4; chunk += gstride) {
        int wbase = chunk + wave * WAVE_SPAN + lane;
        // 16 sequential 4 KB iterations over the wave's 64 KB sub-span
        for (int it = 0; it < 16; ++it) {
            int i = wbase + it * 256;
            if (i + 192 < n4) {
                f32x4 v0 = __builtin_nontemporal_load(&x[i]);
                f32x4 v1 = __builtin_nontemporal_load(&x[i + 64]);
                f32x4 v2 = __builtin_nontemporal_load(&x[i + 128]);
                f32x4 v3 = __builtin_nontemporal_load(&x[i + 192]);
                f32x4 r0 = eval4(v0, s_seg, s_y0, s_k);
                f32x4 r1 = eval4(v1, s_seg, s_y0, s_k);
                f32x4 r2 = eval4(v2, s_seg, s_y0, s_k);
                f32x4 r3 = eval4(v3, s_seg, s_y0, s_k);
                __builtin_nontemporal_store(r0, &out[i]);
                __builtin_nontemporal_store(r1, &out[i + 64]);
                __builtin_nontemporal_store(r2, &out[i + 128]);
                __builtin_nontemporal_store(r3, &out[i + 192]);
            } else {
#pragma unroll
                for (int o = 0; o < 256; o += 64) {
                    if (i + o < n4) {
                        f32x4 v = __builtin_nontemporal_load(&x[i + o]);
                        __builtin_nontemporal_store(
                            eval4(v, s_seg, s_y0, s_k), &out[i + o]);
                    }
                }
            }
        }
    }
}

extern "C" void kernel_launch(void* const* d_in, const int* in_sizes, int n_in,
                              void* d_out, int out_size, void* d_ws, size_t ws_size,
                              hipStream_t stream) {
    const float* x = (const float*)d_in[0];
    float* out = (float*)d_out;
    long long n = in_sizes[0];

    long long n4 = n >> 2;            // n = 32*4096*1024, divisible by 4
    int threads = 256;
    long long chunks = (n4 + BLK_SPAN - 1) / BLK_SPAN;  // 256 KB per block
    int blocks = (int)((chunks < 2048) ? (chunks > 0 ? chunks : 1) : 2048);

    invsqrt16_kernel<<<blocks, threads, 0, stream>>>(
        (const f32x4*)x, (f32x4*)out, (int)n4);

    (void)d_ws; (void)ws_size; (void)n_in; (void)out_size;
}

// Round 10
// 193.183 us; speedup vs baseline: 1.1362x; 1.1362x over previous
//
#include <hip/hip_runtime.h>

typedef float f32x4 __attribute__((ext_vector_type(4)));

// 16-segment breakpoints (module constants from the reference)
__device__ __constant__ float c_seg[16] = {
    0.0001f, 0.002f, 0.004f, 0.007f, 0.01f, 0.03f, 0.1f, 0.2f,
    0.3f,    1.0f,   2.0f,   4.0f,   8.0f,  16.0f, 64.0f, 1024.0f};

__device__ __forceinline__ float eval_seg(float x,
                                          const float* __restrict__ s_seg,
                                          const float* __restrict__ s_y0,
                                          const float* __restrict__ s_k) {
    float xc = fminf(fmaxf(x, 0.0001f), 1024.0f);
    // searchsorted(side='left') - 1, clamped to [0,14]
    int idx = 0;
    idx += (xc > 0.002f);
    idx += (xc > 0.004f);
    idx += (xc > 0.007f);
    idx += (xc > 0.01f);
    idx += (xc > 0.03f);
    idx += (xc > 0.1f);
    idx += (xc > 0.2f);
    idx += (xc > 0.3f);
    idx += (xc > 1.0f);
    idx += (xc > 2.0f);
    idx += (xc > 4.0f);
    idx += (xc > 8.0f);
    idx += (xc > 16.0f);
    idx += (xc > 64.0f);
    // 16 words in 16 distinct banks -> conflict-free gather (R7: the
    // cndmask-cascade VALU alternative was net-worse, 212 vs 200 us)
    float x0 = s_seg[idx];
    float y0 = s_y0[idx];
    float k  = s_k[idx];
    return fmaf(xc - x0, k, y0);
}

__device__ __forceinline__ f32x4 eval4(f32x4 v,
                                       const float* __restrict__ s_seg,
                                       const float* __restrict__ s_y0,
                                       const float* __restrict__ s_k) {
    f32x4 r;
    r.x = eval_seg(v.x, s_seg, s_y0, s_k);
    r.y = eval_seg(v.y, s_seg, s_y0, s_k);
    r.z = eval_seg(v.z, s_seg, s_y0, s_k);
    r.w = eval_seg(v.w, s_seg, s_y0, s_k);
    return r;
}

// Structure ledger: wave-contiguous x4 window (R8, +3%), lockstep grid-stride
// (R9's per-wave sequential spans regressed 13%), nt load+store (R4), LDS
// gather (R7), (256,8) VGPR pin (R2 cliff guard). R10 change: software-
// pipeline across grid-stride iterations — issue iter k+1's 4 nt loads
// BEFORE eval/store of iter k, so loads stay in flight under the eval phase.
__global__ __launch_bounds__(256, 8) void invsqrt16_kernel(
        const f32x4* __restrict__ x, f32x4* __restrict__ out, int n4) {
    __shared__ float s_seg[16];
    __shared__ float s_y0[16];
    __shared__ float s_k[16];
    if (threadIdx.x < 16) {
        int j = threadIdx.x;
        float s0 = c_seg[j];
        float s1 = c_seg[(j < 15) ? j + 1 : 15];
        float y0 = 1.0f / sqrtf(s0);
        float y1 = 1.0f / sqrtf(s1);
        s_seg[j] = s0;
        s_y0[j]  = y0;
        s_k[j]   = (j < 15) ? (y1 - y0) / (s1 - s0) : 0.0f;
    }
    __syncthreads();

    const int lane = threadIdx.x & 63;
    const int wave = threadIdx.x >> 6;
    const int gstride = gridDim.x * 1024;           // f32x4 per grid pass
    int i = blockIdx.x * 1024 + wave * 256 + lane;  // wave owns 4 KB window

    if (i + 192 < n4) {
        // prologue: first window's loads
        f32x4 v0 = __builtin_nontemporal_load(&x[i]);
        f32x4 v1 = __builtin_nontemporal_load(&x[i + 64]);
        f32x4 v2 = __builtin_nontemporal_load(&x[i + 128]);
        f32x4 v3 = __builtin_nontemporal_load(&x[i + 192]);
        while (true) {
            int nx = i + gstride;
            bool more = (nx + 192 < n4);
            f32x4 n0, n1, n2, n3;
            if (more) {
                // next iteration's loads issue BEFORE current eval/store
                n0 = __builtin_nontemporal_load(&x[nx]);
                n1 = __builtin_nontemporal_load(&x[nx + 64]);
                n2 = __builtin_nontemporal_load(&x[nx + 128]);
                n3 = __builtin_nontemporal_load(&x[nx + 192]);
            }
            f32x4 r0 = eval4(v0, s_seg, s_y0, s_k);
            __builtin_nontemporal_store(r0, &out[i]);
            f32x4 r1 = eval4(v1, s_seg, s_y0, s_k);
            __builtin_nontemporal_store(r1, &out[i + 64]);
            f32x4 r2 = eval4(v2, s_seg, s_y0, s_k);
            __builtin_nontemporal_store(r2, &out[i + 128]);
            f32x4 r3 = eval4(v3, s_seg, s_y0, s_k);
            __builtin_nontemporal_store(r3, &out[i + 192]);
            if (!more) break;
            v0 = n0; v1 = n1; v2 = n2; v3 = n3;
            i = nx;
        }
        i += gstride;  // first unprocessed position for this thread
    }
    // ragged tail (never taken for the exact-fit harness size; kept correct)
    for (; i < n4; i += gstride) {
#pragma unroll
        for (int o = 0; o < 256; o += 64) {
            if (i + o < n4) {
                f32x4 v = __builtin_nontemporal_load(&x[i + o]);
                __builtin_nontemporal_store(eval4(v, s_seg, s_y0, s_k),
                                            &out[i + o]);
            }
        }
    }
}

extern "C" void kernel_launch(void* const* d_in, const int* in_sizes, int n_in,
                              void* d_out, int out_size, void* d_ws, size_t ws_size,
                              hipStream_t stream) {
    const float* x = (const float*)d_in[0];
    float* out = (float*)d_out;
    long long n = in_sizes[0];

    long long n4 = n >> 2;            // n = 32*4096*1024, divisible by 4
    int threads = 256;
    long long chunks = (n4 + 1023) / 1024;          // 1024 f32x4 per block pass
    int blocks = (int)((chunks < 2048) ? (chunks > 0 ? chunks : 1) : 2048);

    invsqrt16_kernel<<<blocks, threads, 0, stream>>>(
        (const f32x4*)x, (f32x4*)out, (int)n4);

    (void)d_ws; (void)ws_size; (void)n_in; (void)out_size;
}